// Round 1
// baseline (1609.390 us; speedup 1.0000x reference)
//
#include <hip/hip_runtime.h>
#include <hip/hip_bf16.h>
#include <math.h>

#define N_NODES 50000
#define N_EDGES 800000
#define HDIM 64
#define N_RELS 8
#define N_BASES 2

// ---------------------------------------------------------------------------
// Kernel A: per-node transform.
//   proj[n,b,:] = x[n,:] @ V[b]          (b = 0,1)
//   h[n,:]      = x[n,:] @ loop_w + bias
// x optionally passes through ReLU on read (for layer 1 input).
// Block = 256 threads = 4 nodes x 64 output features. V/loop_w staged in LDS.
// ---------------------------------------------------------------------------
template <bool RELU>
__global__ __launch_bounds__(256) void node_transform(
    const float* __restrict__ x,      // [N, 64]
    const float* __restrict__ V,      // [2, 64, 64]  (this layer)
    const float* __restrict__ loopw,  // [64, 64]     (this layer)
    const float* __restrict__ bias,   // [64]         (this layer)
    float* __restrict__ proj,         // [N, 2, 64]
    float* __restrict__ h)            // [N, 64]
{
    __shared__ float sV0[4096];
    __shared__ float sV1[4096];
    __shared__ float sL[4096];
    __shared__ float sx[256];
    __shared__ float sb[64];

    const int tid = threadIdx.x;

    for (int k = tid; k < 4096; k += 256) {
        sV0[k] = V[k];
        sV1[k] = V[4096 + k];
        sL[k]  = loopw[k];
    }
    {
        float v = x[(size_t)blockIdx.x * 256 + tid];
        if (RELU) v = fmaxf(v, 0.0f);
        sx[tid] = v;
    }
    if (tid < 64) sb[tid] = bias[tid];
    __syncthreads();

    const int o  = tid & 63;
    const int nl = tid >> 6;
    const int n  = blockIdx.x * 4 + nl;

    float acc0 = 0.0f, acc1 = 0.0f, accL = sb[o];
#pragma unroll 8
    for (int i = 0; i < 64; ++i) {
        const float xv = sx[nl * 64 + i];
        acc0 = fmaf(xv, sV0[i * 64 + o], acc0);
        acc1 = fmaf(xv, sV1[i * 64 + o], acc1);
        accL = fmaf(xv, sL[i * 64 + o], accL);
    }
    proj[(size_t)n * 128 + o]      = acc0;
    proj[(size_t)n * 128 + 64 + o] = acc1;
    h[(size_t)n * 64 + o]          = accL;
}

// ---------------------------------------------------------------------------
// Kernel B: edge messages + atomic scatter into h.
//   msg[e,:] = c0 * proj[src,0,:] + c1 * proj[src,1,:]   (c from comp[etype])
//   h[dst,:] += msg[e,:]
// 16 threads per edge, 4 features each (float4 gather, 4 scalar atomics).
// ---------------------------------------------------------------------------
__global__ __launch_bounds__(256) void edge_messages(
    const float* __restrict__ proj,   // [N, 2, 64]
    const int* __restrict__ src,
    const int* __restrict__ dst,
    const int* __restrict__ etype,
    const float* __restrict__ comp,   // [8, 2]  (this layer)
    float* __restrict__ h)            // [N, 64]
{
    const int gid = blockIdx.x * 256 + threadIdx.x;  // E*16 = 12.8M < 2^31
    const int e = gid >> 4;
    const int q = gid & 15;

    const int s = src[e];
    const int d = dst[e];
    const int t = etype[e];
    const float c0 = comp[t * 2 + 0];
    const float c1 = comp[t * 2 + 1];

    const float4 p0 = *(const float4*)(proj + (size_t)s * 128 + q * 4);
    const float4 p1 = *(const float4*)(proj + (size_t)s * 128 + 64 + q * 4);

    float4 m;
    m.x = fmaf(c0, p0.x, c1 * p1.x);
    m.y = fmaf(c0, p0.y, c1 * p1.y);
    m.z = fmaf(c0, p0.z, c1 * p1.z);
    m.w = fmaf(c0, p0.w, c1 * p1.w);

    float* hp = h + (size_t)d * 64 + q * 4;
    atomicAdd(hp + 0, m.x);
    atomicAdd(hp + 1, m.y);
    atomicAdd(hp + 2, m.z);
    atomicAdd(hp + 3, m.w);
}

// ---------------------------------------------------------------------------
// Final: out = sigmoid(sum(h1 * fc_w) + fc_b)
// ---------------------------------------------------------------------------
__global__ __launch_bounds__(256) void final_dot(
    const float* __restrict__ h,      // [N*64] flat
    const float* __restrict__ fcw,    // [N*64] flat
    float* __restrict__ partial)      // [1]
{
    __shared__ float red[256];
    const int nvec = N_NODES * HDIM / 4;  // 800000 float4s
    float acc = 0.0f;
    for (int i = blockIdx.x * 256 + threadIdx.x; i < nvec; i += gridDim.x * 256) {
        const float4 a = ((const float4*)h)[i];
        const float4 b = ((const float4*)fcw)[i];
        acc = fmaf(a.x, b.x, acc);
        acc = fmaf(a.y, b.y, acc);
        acc = fmaf(a.z, b.z, acc);
        acc = fmaf(a.w, b.w, acc);
    }
    red[threadIdx.x] = acc;
    __syncthreads();
    for (int sft = 128; sft > 0; sft >>= 1) {
        if (threadIdx.x < sft) red[threadIdx.x] += red[threadIdx.x + sft];
        __syncthreads();
    }
    if (threadIdx.x == 0) atomicAdd(partial, red[0]);
}

__global__ void final_sigmoid(const float* __restrict__ partial,
                              const float* __restrict__ fcb,
                              float* __restrict__ out)
{
    const float v = partial[0] + fcb[0];
    out[0] = 1.0f / (1.0f + expf(-v));
}

// ---------------------------------------------------------------------------
extern "C" void kernel_launch(void* const* d_in, const int* in_sizes, int n_in,
                              void* d_out, int out_size, void* d_ws, size_t ws_size,
                              hipStream_t stream)
{
    const float* features = (const float*)d_in[0];  // [50000, 64]
    const float* V        = (const float*)d_in[1];  // [2, 2, 64, 64]
    const float* comp     = (const float*)d_in[2];  // [2, 8, 2]
    const float* loop_w   = (const float*)d_in[3];  // [2, 64, 64]
    const float* bias     = (const float*)d_in[4];  // [2, 64]
    const float* fc_w     = (const float*)d_in[5];  // [1, 50000*64]
    const float* fc_b     = (const float*)d_in[6];  // [1]
    const int*   src      = (const int*)d_in[7];
    const int*   dst      = (const int*)d_in[8];
    const int*   etype    = (const int*)d_in[9];
    float* out = (float*)d_out;

    char* ws = (char*)d_ws;
    float* proj   = (float*)(ws);                      // 50000*128 f32 = 25.6 MB
    float* h0     = (float*)(ws + 25600000);           // 12.8 MB
    float* h1     = (float*)(ws + 38400000);           // 12.8 MB
    float* scalar = (float*)(ws + 51200000);           // 4 B

    hipMemsetAsync(scalar, 0, sizeof(float), stream);

    const int ntBlocks   = N_NODES / 4;        // 12500
    const int edgeBlocks = N_EDGES * 16 / 256; // 50000

    // ----- layer 0 -----
    node_transform<false><<<ntBlocks, 256, 0, stream>>>(
        features, V, loop_w, bias, proj, h0);
    edge_messages<<<edgeBlocks, 256, 0, stream>>>(
        proj, src, dst, etype, comp, h0);

    // ----- layer 1 (ReLU on input) -----
    node_transform<true><<<ntBlocks, 256, 0, stream>>>(
        h0, V + 2 * 64 * 64, loop_w + 64 * 64, bias + 64, proj, h1);
    edge_messages<<<edgeBlocks, 256, 0, stream>>>(
        proj, src, dst, etype, comp + 8 * 2, h1);

    // ----- FC + sigmoid -----
    final_dot<<<1024, 256, 0, stream>>>(h1, fc_w, scalar);
    final_sigmoid<<<1, 1, 0, stream>>>(scalar, fc_b, out);
}

// Round 2
// 463.350 us; speedup vs baseline: 3.4734x; 3.4734x over previous
//
#include <hip/hip_runtime.h>
#include <hip/hip_bf16.h>
#include <math.h>

#define N_NODES 50000
#define N_EDGES 800000
#define HDIM 64

// ---------------------------------------------------------------------------
// CSR build: histogram of dst, exclusive scan, scatter edges (src|etype packed)
// ---------------------------------------------------------------------------
__global__ __launch_bounds__(256) void hist_kernel(
    const int* __restrict__ dst, int* __restrict__ deg)
{
    const int e = blockIdx.x * 256 + threadIdx.x;
    atomicAdd(&deg[dst[e]], 1);
}

__global__ __launch_bounds__(512) void scan_rowptr(
    const int* __restrict__ deg, int* __restrict__ row_ptr)
{
    __shared__ int s[512];
    const int t = threadIdx.x;
    const int base = t * 98;              // 512*98 = 50176 >= 50000
    int local = 0;
    for (int i = 0; i < 98; ++i) {
        int idx = base + i;
        if (idx < N_NODES) local += deg[idx];
    }
    s[t] = local;
    __syncthreads();
    for (int off = 1; off < 512; off <<= 1) {
        int v = (t >= off) ? s[t - off] : 0;
        __syncthreads();
        s[t] += v;
        __syncthreads();
    }
    int run = (t == 0) ? 0 : s[t - 1];
    for (int i = 0; i < 98; ++i) {
        int idx = base + i;
        if (idx < N_NODES) { row_ptr[idx] = run; run += deg[idx]; }
    }
    if (t == 511) row_ptr[N_NODES] = s[511];
}

__global__ __launch_bounds__(256) void scatter_kernel(
    const int* __restrict__ src, const int* __restrict__ dst,
    const int* __restrict__ etype, const int* __restrict__ row_ptr,
    int* __restrict__ fill, unsigned int* __restrict__ edges)
{
    const int e = blockIdx.x * 256 + threadIdx.x;
    const int d = dst[e];
    const int pos = row_ptr[d] + atomicAdd(&fill[d], 1);
    edges[pos] = (unsigned int)src[e] | ((unsigned int)etype[e] << 16);
}

// ---------------------------------------------------------------------------
// Aggregate (basis domain): y[n,b,:] = sum_{e: dst=n} comp[etype_e][b] * x[src_e,:]
// One wave per node, lane = feature. No atomics.
// ---------------------------------------------------------------------------
template <bool RELU>
__global__ __launch_bounds__(256) void aggregate(
    const float* __restrict__ x,        // [N,64]
    const unsigned int* __restrict__ edges,
    const int* __restrict__ row_ptr,
    const float* __restrict__ comp_l,   // [8,2]
    float* __restrict__ y)              // [N,128]
{
    const int o = threadIdx.x & 63;
    const int n = blockIdx.x * 4 + (threadIdx.x >> 6);
    int j = row_ptr[n];
    const int end = row_ptr[n + 1];
    float y0 = 0.f, y1 = 0.f;
    for (; j + 1 < end; j += 2) {            // 2 independent gather chains
        const unsigned pk0 = edges[j], pk1 = edges[j + 1];
        float xv0 = x[(pk0 & 0xFFFFu) * 64 + o];
        float xv1 = x[(pk1 & 0xFFFFu) * 64 + o];
        const float2 c0 = *(const float2*)&comp_l[(pk0 >> 16) * 2];
        const float2 c1 = *(const float2*)&comp_l[(pk1 >> 16) * 2];
        if (RELU) { xv0 = fmaxf(xv0, 0.f); xv1 = fmaxf(xv1, 0.f); }
        y0 = fmaf(c0.x, xv0, y0); y1 = fmaf(c0.y, xv0, y1);
        y0 = fmaf(c1.x, xv1, y0); y1 = fmaf(c1.y, xv1, y1);
    }
    if (j < end) {
        const unsigned pk = edges[j];
        float xv = x[(pk & 0xFFFFu) * 64 + o];
        const float2 c = *(const float2*)&comp_l[(pk >> 16) * 2];
        if (RELU) xv = fmaxf(xv, 0.f);
        y0 = fmaf(c.x, xv, y0); y1 = fmaf(c.y, xv, y1);
    }
    y[(size_t)n * 128 + o]      = y0;
    y[(size_t)n * 128 + 64 + o] = y1;
}

// ---------------------------------------------------------------------------
// Node transform: h[n,:] = [y0,y1,relu?(x)] @ [V0;V1;L] + bias   (stacked GEMM)
// Block = 256 threads = 16 nodes x 16 output-quads; float4 LDS reads.
// FUSE: instead of storing h, dot with fc_w and atomically reduce to scalar.
// ---------------------------------------------------------------------------
template <bool RELU, bool FUSE>
__global__ __launch_bounds__(256) void node_transform(
    const float* __restrict__ x,      // [N,64]
    const float* __restrict__ y,      // [N,128]
    const float* __restrict__ Vl,     // [2,64,64] this layer
    const float* __restrict__ lw,     // [64,64]   this layer
    const float* __restrict__ bias,   // [64]
    const float* __restrict__ fcw,    // [N*64] (FUSE only)
    float* __restrict__ h,            // [N,64] (!FUSE only)
    float* __restrict__ scalar)       // [1]    (FUSE only)
{
    __shared__ float sW[192 * 64];
    __shared__ float su[16 * 196];    // 192 + 4 pad: kills 4-way bank alias
    __shared__ float sb[64];
    __shared__ float sred[4];
    const int t = threadIdx.x;

    {   // stage stacked weights [V0;V1;L]
        const float4* V4 = (const float4*)Vl;
        const float4* L4 = (const float4*)lw;
        float4* W4 = (float4*)sW;
#pragma unroll
        for (int k = 0; k < 12; ++k) {
            const int i4 = t + 256 * k;            // 0..3071
            W4[i4] = (i4 < 2048) ? V4[i4] : L4[i4 - 2048];
        }
    }
    {   // stage u = [y0,y1,x] for 16 nodes
#pragma unroll
        for (int k = 0; k < 3; ++k) {
            const int idx4 = t + 256 * k;          // 0..767
            const int node = idx4 / 48;
            const int part = idx4 % 48;
            const int gn = blockIdx.x * 16 + node;
            float4 v;
            if (part < 32) {
                v = ((const float4*)(y + (size_t)gn * 128))[part];
            } else {
                v = ((const float4*)(x + (size_t)gn * 64))[part - 32];
                if (RELU) {
                    v.x = fmaxf(v.x, 0.f); v.y = fmaxf(v.y, 0.f);
                    v.z = fmaxf(v.z, 0.f); v.w = fmaxf(v.w, 0.f);
                }
            }
            *(float4*)&su[node * 196 + part * 4] = v;
        }
    }
    if (t < 64) sb[t] = bias[t];
    __syncthreads();

    const int q  = t & 15;
    const int nl = t >> 4;
    const int gn = blockIdx.x * 16 + nl;
    float4 acc = { sb[4 * q], sb[4 * q + 1], sb[4 * q + 2], sb[4 * q + 3] };

#pragma unroll 4
    for (int i4 = 0; i4 < 48; ++i4) {
        const float4 uv = *(const float4*)&su[nl * 196 + 4 * i4];
        const float* wr = &sW[(4 * i4) * 64 + 4 * q];
        const float4 w0 = *(const float4*)(wr);
        const float4 w1 = *(const float4*)(wr + 64);
        const float4 w2 = *(const float4*)(wr + 128);
        const float4 w3 = *(const float4*)(wr + 192);
        acc.x = fmaf(uv.x, w0.x, acc.x); acc.y = fmaf(uv.x, w0.y, acc.y);
        acc.z = fmaf(uv.x, w0.z, acc.z); acc.w = fmaf(uv.x, w0.w, acc.w);
        acc.x = fmaf(uv.y, w1.x, acc.x); acc.y = fmaf(uv.y, w1.y, acc.y);
        acc.z = fmaf(uv.y, w1.z, acc.z); acc.w = fmaf(uv.y, w1.w, acc.w);
        acc.x = fmaf(uv.z, w2.x, acc.x); acc.y = fmaf(uv.z, w2.y, acc.y);
        acc.z = fmaf(uv.z, w2.z, acc.z); acc.w = fmaf(uv.z, w2.w, acc.w);
        acc.x = fmaf(uv.w, w3.x, acc.x); acc.y = fmaf(uv.w, w3.y, acc.y);
        acc.z = fmaf(uv.w, w3.z, acc.z); acc.w = fmaf(uv.w, w3.w, acc.w);
    }

    if (FUSE) {
        const float4 fw = *(const float4*)&fcw[(size_t)gn * 64 + 4 * q];
        float p = acc.x * fw.x + acc.y * fw.y + acc.z * fw.z + acc.w * fw.w;
#pragma unroll
        for (int off = 32; off; off >>= 1) p += __shfl_down(p, off, 64);
        if ((t & 63) == 0) sred[t >> 6] = p;
        __syncthreads();
        if (t == 0) atomicAdd(scalar, sred[0] + sred[1] + sred[2] + sred[3]);
    } else {
        *(float4*)&h[(size_t)gn * 64 + 4 * q] = acc;
    }
}

__global__ void final_sigmoid(const float* __restrict__ scalar,
                              const float* __restrict__ fcb,
                              float* __restrict__ out)
{
    const float v = scalar[0] + fcb[0];
    out[0] = 1.0f / (1.0f + expf(-v));
}

// ---------------------------------------------------------------------------
extern "C" void kernel_launch(void* const* d_in, const int* in_sizes, int n_in,
                              void* d_out, int out_size, void* d_ws, size_t ws_size,
                              hipStream_t stream)
{
    const float* features = (const float*)d_in[0];  // [50000, 64]
    const float* V        = (const float*)d_in[1];  // [2, 2, 64, 64]
    const float* comp     = (const float*)d_in[2];  // [2, 8, 2]
    const float* loop_w   = (const float*)d_in[3];  // [2, 64, 64]
    const float* bias     = (const float*)d_in[4];  // [2, 64]
    const float* fc_w     = (const float*)d_in[5];  // [1, 50000*64]
    const float* fc_b     = (const float*)d_in[6];  // [1]
    const int*   src      = (const int*)d_in[7];
    const int*   dst      = (const int*)d_in[8];
    const int*   etype    = (const int*)d_in[9];
    float* out = (float*)d_out;

    char* ws = (char*)d_ws;
    float*        y       = (float*)(ws);                        // 25,600,000 B
    float*        h0      = (float*)(ws + 25600000);             // 12,800,000 B
    float*        scalar  = (float*)(ws + 38400000);             // 4 B (pad 256)
    int*          deg     = (int*)  (ws + 38400256);             // 200,000 B
    int*          fill    = (int*)  (ws + 38600256);             // 200,000 B
    int*          row_ptr = (int*)  (ws + 38800256);             // 200,004 B
    unsigned int* edges   = (unsigned int*)(ws + 39000320);      // 3,200,000 B
                                                                 // end ~42.2 MB

    // zero deg+fill (contiguous) and scalar
    hipMemsetAsync(deg, 0, 400000, stream);
    hipMemsetAsync(scalar, 0, 4, stream);

    const int edgeBlocks = N_EDGES / 256;   // 3125
    const int aggBlocks  = N_NODES / 4;     // 12500
    const int ntBlocks   = N_NODES / 16;    // 3125

    // ---- CSR build (same every call; rebuilt per graph-capture rules) ----
    hist_kernel<<<edgeBlocks, 256, 0, stream>>>(dst, deg);
    scan_rowptr<<<1, 512, 0, stream>>>(deg, row_ptr);
    scatter_kernel<<<edgeBlocks, 256, 0, stream>>>(src, dst, etype, row_ptr, fill, edges);

    // ---- layer 0 ----
    aggregate<false><<<aggBlocks, 256, 0, stream>>>(features, edges, row_ptr, comp, y);
    node_transform<false, false><<<ntBlocks, 256, 0, stream>>>(
        features, y, V, loop_w, bias, nullptr, h0, nullptr);

    // ---- layer 1 (ReLU on inputs) + fused FC dot ----
    aggregate<true><<<aggBlocks, 256, 0, stream>>>(h0, edges, row_ptr, comp + 16, y);
    node_transform<true, true><<<ntBlocks, 256, 0, stream>>>(
        h0, y, V + 8192, loop_w + 4096, bias + 64, fc_w, nullptr, scalar);

    // ---- sigmoid ----
    final_sigmoid<<<1, 1, 0, stream>>>(scalar, fc_b, out);
}

// Round 3
// 319.675 us; speedup vs baseline: 5.0344x; 1.4494x over previous
//
#include <hip/hip_runtime.h>
#include <hip/hip_bf16.h>
#include <math.h>

#define N_NODES 50000
#define N_EDGES 800000
#define HDIM 64
#define SCAN_BLOCKS 196   // 196*256 = 50176 >= 50000

// ---------------------------------------------------------------------------
// CSR build: histogram of dst -> 3-kernel coalesced scan -> scatter
// edges[] packs src (16 bits, N_NODES<65536) | etype<<16
// ---------------------------------------------------------------------------
__global__ __launch_bounds__(256) void hist_kernel(
    const int* __restrict__ dst, int* __restrict__ deg)
{
    const int e = blockIdx.x * 256 + threadIdx.x;
    atomicAdd(&deg[dst[e]], 1);
}

// block sums of deg (coalesced)
__global__ __launch_bounds__(256) void scan_block_sums(
    const int* __restrict__ deg, int* __restrict__ bsum)
{
    __shared__ int s[256];
    const int idx = blockIdx.x * 256 + threadIdx.x;
    s[threadIdx.x] = (idx < N_NODES) ? deg[idx] : 0;
    __syncthreads();
    for (int off = 128; off; off >>= 1) {
        if (threadIdx.x < off) s[threadIdx.x] += s[threadIdx.x + off];
        __syncthreads();
    }
    if (threadIdx.x == 0) bsum[blockIdx.x] = s[0];
}

// scan the 196 block sums -> exclusive block offsets; also writes row_ptr[N]
// and zeroes the fused-dot scalar.
__global__ __launch_bounds__(256) void scan_offsets(
    const int* __restrict__ bsum, int* __restrict__ bofs,
    int* __restrict__ row_ptr, float* __restrict__ scalar)
{
    __shared__ int s[256];
    const int t = threadIdx.x;
    const int v = (t < SCAN_BLOCKS) ? bsum[t] : 0;
    s[t] = v;
    __syncthreads();
    for (int off = 1; off < 256; off <<= 1) {
        int u = (t >= off) ? s[t - off] : 0;
        __syncthreads();
        s[t] += u;
        __syncthreads();
    }
    if (t < SCAN_BLOCKS) bofs[t] = s[t] - v;      // exclusive
    if (t == 255) row_ptr[N_NODES] = s[255];      // total = N_EDGES
    if (t == 0) scalar[0] = 0.0f;
}

// block-local inclusive scan + block offset -> row_ptr (exclusive overall)
__global__ __launch_bounds__(256) void scan_final(
    const int* __restrict__ deg, const int* __restrict__ bofs,
    int* __restrict__ row_ptr)
{
    __shared__ int s[256];
    const int t = threadIdx.x;
    const int idx = blockIdx.x * 256 + t;
    const int v = (idx < N_NODES) ? deg[idx] : 0;
    s[t] = v;
    __syncthreads();
    for (int off = 1; off < 256; off <<= 1) {
        int u = (t >= off) ? s[t - off] : 0;
        __syncthreads();
        s[t] += u;
        __syncthreads();
    }
    if (idx < N_NODES) row_ptr[idx] = bofs[blockIdx.x] + s[t] - v;
}

__global__ __launch_bounds__(256) void scatter_kernel(
    const int* __restrict__ src, const int* __restrict__ dst,
    const int* __restrict__ etype, const int* __restrict__ row_ptr,
    int* __restrict__ fill, unsigned int* __restrict__ edges)
{
    const int e = blockIdx.x * 256 + threadIdx.x;
    const int d = dst[e];
    const int pos = row_ptr[d] + atomicAdd(&fill[d], 1);
    edges[pos] = (unsigned int)src[e] | ((unsigned int)etype[e] << 16);
}

// ---------------------------------------------------------------------------
// Aggregate: y[n,b,:] = sum_{e: dst=n} comp[etype_e][b] * relu?(x[src_e,:])
// One wave per node. Lane layout: g = lane>>4 (edge slot 0..3),
// fq = lane&15 (feature quad). Each iteration covers 8 edges (2 masked slots),
// each lane issuing 2 independent float4 gathers -> 8 x-rows in flight/wave.
// Final 2-step shfl_xor butterfly folds the 4 edge groups. No atomics.
// ---------------------------------------------------------------------------
__device__ __forceinline__ float4 shfl_xor4(float4 v, int m) {
    float4 r;
    r.x = __shfl_xor(v.x, m, 64);
    r.y = __shfl_xor(v.y, m, 64);
    r.z = __shfl_xor(v.z, m, 64);
    r.w = __shfl_xor(v.w, m, 64);
    return r;
}

template <bool RELU>
__global__ __launch_bounds__(256) void aggregate(
    const float* __restrict__ x,        // [N,64]
    const unsigned int* __restrict__ edges,
    const int* __restrict__ row_ptr,
    const float* __restrict__ comp_l,   // [8,2]
    float* __restrict__ y)              // [N,128]
{
    const int lane = threadIdx.x & 63;
    const int n    = blockIdx.x * 4 + (threadIdx.x >> 6);
    const int g    = lane >> 4;         // edge slot within wave
    const int fq   = lane & 15;         // feature quad

    const int beg = row_ptr[n];
    const int end = row_ptr[n + 1];

    float4 a0 = {0.f, 0.f, 0.f, 0.f};
    float4 a1 = {0.f, 0.f, 0.f, 0.f};

    for (int j = beg; j < end; j += 8) {
        const int j0 = j + g;
        const int j1 = j + 4 + g;
        const unsigned pk0 = edges[(j0 < end) ? j0 : (end - 1)];
        const unsigned pk1 = edges[(j1 < end) ? j1 : (end - 1)];
        float2 c0 = *(const float2*)&comp_l[(pk0 >> 16) * 2];
        float2 c1 = *(const float2*)&comp_l[(pk1 >> 16) * 2];
        if (j0 >= end) { c0.x = 0.f; c0.y = 0.f; }
        if (j1 >= end) { c1.x = 0.f; c1.y = 0.f; }
        float4 x0 = *(const float4*)&x[(pk0 & 0xFFFFu) * 64 + fq * 4];
        float4 x1 = *(const float4*)&x[(pk1 & 0xFFFFu) * 64 + fq * 4];
        if (RELU) {
            x0.x = fmaxf(x0.x, 0.f); x0.y = fmaxf(x0.y, 0.f);
            x0.z = fmaxf(x0.z, 0.f); x0.w = fmaxf(x0.w, 0.f);
            x1.x = fmaxf(x1.x, 0.f); x1.y = fmaxf(x1.y, 0.f);
            x1.z = fmaxf(x1.z, 0.f); x1.w = fmaxf(x1.w, 0.f);
        }
        a0.x = fmaf(c0.x, x0.x, a0.x); a0.y = fmaf(c0.x, x0.y, a0.y);
        a0.z = fmaf(c0.x, x0.z, a0.z); a0.w = fmaf(c0.x, x0.w, a0.w);
        a1.x = fmaf(c0.y, x0.x, a1.x); a1.y = fmaf(c0.y, x0.y, a1.y);
        a1.z = fmaf(c0.y, x0.z, a1.z); a1.w = fmaf(c0.y, x0.w, a1.w);
        a0.x = fmaf(c1.x, x1.x, a0.x); a0.y = fmaf(c1.x, x1.y, a0.y);
        a0.z = fmaf(c1.x, x1.z, a0.z); a0.w = fmaf(c1.x, x1.w, a0.w);
        a1.x = fmaf(c1.y, x1.x, a1.x); a1.y = fmaf(c1.y, x1.y, a1.y);
        a1.z = fmaf(c1.y, x1.z, a1.z); a1.w = fmaf(c1.y, x1.w, a1.w);
    }

    // fold edge slots: butterfly over lane bits 4,5
    a0 = a0; a1 = a1;
    {
        float4 t0 = shfl_xor4(a0, 16), t1 = shfl_xor4(a1, 16);
        a0.x += t0.x; a0.y += t0.y; a0.z += t0.z; a0.w += t0.w;
        a1.x += t1.x; a1.y += t1.y; a1.z += t1.z; a1.w += t1.w;
        t0 = shfl_xor4(a0, 32); t1 = shfl_xor4(a1, 32);
        a0.x += t0.x; a0.y += t0.y; a0.z += t0.z; a0.w += t0.w;
        a1.x += t1.x; a1.y += t1.y; a1.z += t1.z; a1.w += t1.w;
    }
    if (g == 0) {
        *(float4*)&y[(size_t)n * 128 + fq * 4]      = a0;
        *(float4*)&y[(size_t)n * 128 + 64 + fq * 4] = a1;
    }
}

// ---------------------------------------------------------------------------
// Node transform: h[n,:] = [y0,y1,relu?(x)] @ [V0;V1;L] + bias   (stacked GEMM)
// Block = 256 threads = 16 nodes x 16 output-quads; float4 LDS reads.
// FUSE: dot with fc_w and atomically reduce to scalar instead of storing h.
// ---------------------------------------------------------------------------
template <bool RELU, bool FUSE>
__global__ __launch_bounds__(256) void node_transform(
    const float* __restrict__ x,      // [N,64]
    const float* __restrict__ y,      // [N,128]
    const float* __restrict__ Vl,     // [2,64,64] this layer
    const float* __restrict__ lw,     // [64,64]   this layer
    const float* __restrict__ bias,   // [64]
    const float* __restrict__ fcw,    // [N*64] (FUSE only)
    float* __restrict__ h,            // [N,64] (!FUSE only)
    float* __restrict__ scalar)       // [1]    (FUSE only)
{
    __shared__ float sW[192 * 64];
    __shared__ float su[16 * 196];    // 192 + 4 pad
    __shared__ float sb[64];
    __shared__ float sred[4];
    const int t = threadIdx.x;

    {   // stage stacked weights [V0;V1;L]
        const float4* V4 = (const float4*)Vl;
        const float4* L4 = (const float4*)lw;
        float4* W4 = (float4*)sW;
#pragma unroll
        for (int k = 0; k < 12; ++k) {
            const int i4 = t + 256 * k;            // 0..3071
            W4[i4] = (i4 < 2048) ? V4[i4] : L4[i4 - 2048];
        }
    }
    {   // stage u = [y0,y1,x] for 16 nodes
#pragma unroll
        for (int k = 0; k < 3; ++k) {
            const int idx4 = t + 256 * k;          // 0..767
            const int node = idx4 / 48;
            const int part = idx4 % 48;
            const int gn = blockIdx.x * 16 + node;
            float4 v;
            if (part < 32) {
                v = ((const float4*)(y + (size_t)gn * 128))[part];
            } else {
                v = ((const float4*)(x + (size_t)gn * 64))[part - 32];
                if (RELU) {
                    v.x = fmaxf(v.x, 0.f); v.y = fmaxf(v.y, 0.f);
                    v.z = fmaxf(v.z, 0.f); v.w = fmaxf(v.w, 0.f);
                }
            }
            *(float4*)&su[node * 196 + part * 4] = v;
        }
    }
    if (t < 64) sb[t] = bias[t];
    __syncthreads();

    const int q  = t & 15;
    const int nl = t >> 4;
    const int gn = blockIdx.x * 16 + nl;
    float4 acc = { sb[4 * q], sb[4 * q + 1], sb[4 * q + 2], sb[4 * q + 3] };

#pragma unroll 4
    for (int i4 = 0; i4 < 48; ++i4) {
        const float4 uv = *(const float4*)&su[nl * 196 + 4 * i4];
        const float* wr = &sW[(4 * i4) * 64 + 4 * q];
        const float4 w0 = *(const float4*)(wr);
        const float4 w1 = *(const float4*)(wr + 64);
        const float4 w2 = *(const float4*)(wr + 128);
        const float4 w3 = *(const float4*)(wr + 192);
        acc.x = fmaf(uv.x, w0.x, acc.x); acc.y = fmaf(uv.x, w0.y, acc.y);
        acc.z = fmaf(uv.x, w0.z, acc.z); acc.w = fmaf(uv.x, w0.w, acc.w);
        acc.x = fmaf(uv.y, w1.x, acc.x); acc.y = fmaf(uv.y, w1.y, acc.y);
        acc.z = fmaf(uv.y, w1.z, acc.z); acc.w = fmaf(uv.y, w1.w, acc.w);
        acc.x = fmaf(uv.z, w2.x, acc.x); acc.y = fmaf(uv.z, w2.y, acc.y);
        acc.z = fmaf(uv.z, w2.z, acc.z); acc.w = fmaf(uv.z, w2.w, acc.w);
        acc.x = fmaf(uv.w, w3.x, acc.x); acc.y = fmaf(uv.w, w3.y, acc.y);
        acc.z = fmaf(uv.w, w3.z, acc.z); acc.w = fmaf(uv.w, w3.w, acc.w);
    }

    if (FUSE) {
        const float4 fw = *(const float4*)&fcw[(size_t)gn * 64 + 4 * q];
        float p = acc.x * fw.x + acc.y * fw.y + acc.z * fw.z + acc.w * fw.w;
#pragma unroll
        for (int off = 32; off; off >>= 1) p += __shfl_down(p, off, 64);
        if ((t & 63) == 0) sred[t >> 6] = p;
        __syncthreads();
        if (t == 0) atomicAdd(scalar, sred[0] + sred[1] + sred[2] + sred[3]);
    } else {
        *(float4*)&h[(size_t)gn * 64 + 4 * q] = acc;
    }
}

__global__ void final_sigmoid(const float* __restrict__ scalar,
                              const float* __restrict__ fcb,
                              float* __restrict__ out)
{
    const float v = scalar[0] + fcb[0];
    out[0] = 1.0f / (1.0f + expf(-v));
}

// ---------------------------------------------------------------------------
extern "C" void kernel_launch(void* const* d_in, const int* in_sizes, int n_in,
                              void* d_out, int out_size, void* d_ws, size_t ws_size,
                              hipStream_t stream)
{
    const float* features = (const float*)d_in[0];  // [50000, 64]
    const float* V        = (const float*)d_in[1];  // [2, 2, 64, 64]
    const float* comp     = (const float*)d_in[2];  // [2, 8, 2]
    const float* loop_w   = (const float*)d_in[3];  // [2, 64, 64]
    const float* bias     = (const float*)d_in[4];  // [2, 64]
    const float* fc_w     = (const float*)d_in[5];  // [1, 50000*64]
    const float* fc_b     = (const float*)d_in[6];  // [1]
    const int*   src      = (const int*)d_in[7];
    const int*   dst      = (const int*)d_in[8];
    const int*   etype    = (const int*)d_in[9];
    float* out = (float*)d_out;

    char* ws = (char*)d_ws;
    float*        y       = (float*)(ws);                        // 25,600,000 B
    float*        h0      = (float*)(ws + 25600000);             // 12,800,000 B
    float*        scalar  = (float*)(ws + 38400000);             // 4 B (pad 256)
    int*          deg     = (int*)  (ws + 38400256);             // 200,000 B
    int*          fill    = (int*)  (ws + 38600256);             // 200,000 B
    int*          row_ptr = (int*)  (ws + 38800256);             // 200,004 B
    unsigned int* edges   = (unsigned int*)(ws + 39000320);      // 3,200,000 B
    int*          bsum    = (int*)  (ws + 42200320);             // 784 B
    int*          bofs    = (int*)  (ws + 42201152);             // 784 B

    hipMemsetAsync(deg, 0, 400000, stream);   // deg + fill (contiguous)

    const int edgeBlocks = N_EDGES / 256;   // 3125
    const int aggBlocks  = N_NODES / 4;     // 12500
    const int ntBlocks   = N_NODES / 16;    // 3125

    // ---- CSR build ----
    hist_kernel<<<edgeBlocks, 256, 0, stream>>>(dst, deg);
    scan_block_sums<<<SCAN_BLOCKS, 256, 0, stream>>>(deg, bsum);
    scan_offsets<<<1, 256, 0, stream>>>(bsum, bofs, row_ptr, scalar);
    scan_final<<<SCAN_BLOCKS, 256, 0, stream>>>(deg, bofs, row_ptr);
    scatter_kernel<<<edgeBlocks, 256, 0, stream>>>(src, dst, etype, row_ptr, fill, edges);

    // ---- layer 0 ----
    aggregate<false><<<aggBlocks, 256, 0, stream>>>(features, edges, row_ptr, comp, y);
    node_transform<false, false><<<ntBlocks, 256, 0, stream>>>(
        features, y, V, loop_w, bias, nullptr, h0, nullptr);

    // ---- layer 1 (ReLU on inputs) + fused FC dot ----
    aggregate<true><<<aggBlocks, 256, 0, stream>>>(h0, edges, row_ptr, comp + 16, y);
    node_transform<true, true><<<ntBlocks, 256, 0, stream>>>(
        h0, y, V + 8192, loop_w + 4096, bias + 64, fc_w, nullptr, scalar);

    // ---- sigmoid ----
    final_sigmoid<<<1, 1, 0, stream>>>(scalar, fc_b, out);
}

// Round 4
// 257.544 us; speedup vs baseline: 6.2490x; 1.2412x over previous
//
#include <hip/hip_runtime.h>
#include <hip/hip_bf16.h>
#include <math.h>

#define N_NODES 50000
#define N_EDGES 800000
#define HDIM 64
#define SCAN_BLOCKS 196   // 196*256 = 50176 >= 50000

typedef short bf16x8 __attribute__((ext_vector_type(8)));
typedef float f32x4  __attribute__((ext_vector_type(4)));
typedef unsigned short ushort_t;

__device__ __forceinline__ ushort_t f2bf(float f) {
    __hip_bfloat16 b = __float2bfloat16(f);
    return *(ushort_t*)&b;
}
__device__ __forceinline__ void unpack8(uint4 u, float* f) {
    f[0] = __uint_as_float(u.x << 16); f[1] = __uint_as_float(u.x & 0xFFFF0000u);
    f[2] = __uint_as_float(u.y << 16); f[3] = __uint_as_float(u.y & 0xFFFF0000u);
    f[4] = __uint_as_float(u.z << 16); f[5] = __uint_as_float(u.z & 0xFFFF0000u);
    f[6] = __uint_as_float(u.w << 16); f[7] = __uint_as_float(u.w & 0xFFFF0000u);
}

// ---------------------------------------------------------------------------
// Fused prep: [0,3125) dst histogram; [3125,6250) features->bf16;
// [6250,6346) stacked W transpose+convert: Wt[l][n=out][k=in-stacked] bf16.
// ---------------------------------------------------------------------------
__global__ __launch_bounds__(256) void prep_kernel(
    const int* __restrict__ dst, int* __restrict__ deg,
    const float* __restrict__ features, ushort_t* __restrict__ x_bf,
    const float* __restrict__ V, const float* __restrict__ lw,
    ushort_t* __restrict__ Wt)
{
    const int b = blockIdx.x;
    const int t = threadIdx.x;
    if (b < 3125) {
        const int e = b * 256 + t;
        atomicAdd(&deg[dst[e]], 1);
    } else if (b < 6250) {
        const int i = (b - 3125) * 256 + t;          // < 800000
        const float4 v = ((const float4*)features)[i];
        ushort4 o = { f2bf(v.x), f2bf(v.y), f2bf(v.z), f2bf(v.w) };
        *(ushort4*)&x_bf[(size_t)i * 4] = o;
    } else {
        const int e = (b - 6250) * 256 + t;          // < 24576
        const int l = e / 12288, r = e % 12288;
        const int n = r / 192, k = r % 192;
        const int sel = k >> 6, i = k & 63;
        const float val = (sel < 2) ? V[l * 8192 + sel * 4096 + i * 64 + n]
                                    : lw[l * 4096 + i * 64 + n];
        Wt[e] = f2bf(val);
    }
}

// ---------------------------------------------------------------------------
// Coalesced 3-kernel scan for row_ptr
// ---------------------------------------------------------------------------
__global__ __launch_bounds__(256) void scan_block_sums(
    const int* __restrict__ deg, int* __restrict__ bsum)
{
    __shared__ int s[256];
    const int idx = blockIdx.x * 256 + threadIdx.x;
    s[threadIdx.x] = (idx < N_NODES) ? deg[idx] : 0;
    __syncthreads();
    for (int off = 128; off; off >>= 1) {
        if (threadIdx.x < off) s[threadIdx.x] += s[threadIdx.x + off];
        __syncthreads();
    }
    if (threadIdx.x == 0) bsum[blockIdx.x] = s[0];
}

__global__ __launch_bounds__(256) void scan_offsets(
    const int* __restrict__ bsum, int* __restrict__ bofs,
    int* __restrict__ row_ptr, float* __restrict__ scalar)
{
    __shared__ int s[256];
    const int t = threadIdx.x;
    const int v = (t < SCAN_BLOCKS) ? bsum[t] : 0;
    s[t] = v;
    __syncthreads();
    for (int off = 1; off < 256; off <<= 1) {
        int u = (t >= off) ? s[t - off] : 0;
        __syncthreads();
        s[t] += u;
        __syncthreads();
    }
    if (t < SCAN_BLOCKS) bofs[t] = s[t] - v;
    if (t == 255) row_ptr[N_NODES] = s[255];
    if (t == 0) scalar[0] = 0.0f;
}

__global__ __launch_bounds__(256) void scan_final(
    const int* __restrict__ deg, const int* __restrict__ bofs,
    int* __restrict__ row_ptr)
{
    __shared__ int s[256];
    const int t = threadIdx.x;
    const int idx = blockIdx.x * 256 + t;
    const int v = (idx < N_NODES) ? deg[idx] : 0;
    s[t] = v;
    __syncthreads();
    for (int off = 1; off < 256; off <<= 1) {
        int u = (t >= off) ? s[t - off] : 0;
        __syncthreads();
        s[t] += u;
        __syncthreads();
    }
    if (idx < N_NODES) row_ptr[idx] = bofs[blockIdx.x] + s[t] - v;
}

__global__ __launch_bounds__(256) void scatter_kernel(
    const int* __restrict__ src, const int* __restrict__ dst,
    const int* __restrict__ etype, const int* __restrict__ row_ptr,
    int* __restrict__ fill, unsigned int* __restrict__ edges)
{
    const int e = blockIdx.x * 256 + threadIdx.x;
    const int d = dst[e];
    const int pos = row_ptr[d] + atomicAdd(&fill[d], 1);
    edges[pos] = (unsigned int)src[e] | ((unsigned int)etype[e] << 16);
}

// ---------------------------------------------------------------------------
// Aggregate (bf16 gather, f32 accumulate, bf16 out):
//   y[n,b,:] = sum_{e: dst=n} comp[etype_e][b] * x[src_e,:]
// One wave per node; 8 edge slots (g) x 8 feature-octets (fo); 2 chains
// -> 16 edges in flight per iteration. Butterfly fold over lane bits 3..5.
// ---------------------------------------------------------------------------
__global__ __launch_bounds__(256) void aggregate_bf(
    const ushort_t* __restrict__ x,      // [N,64] bf16
    const unsigned int* __restrict__ edges,
    const int* __restrict__ row_ptr,
    const float* __restrict__ comp_l,    // [8,2] f32
    ushort_t* __restrict__ y)            // [N,128] bf16
{
    const int lane = threadIdx.x & 63;
    const int n    = blockIdx.x * 4 + (threadIdx.x >> 6);
    const int g    = lane >> 3;
    const int fo   = lane & 7;

    const int beg = row_ptr[n];
    const int end = row_ptr[n + 1];

    float a0[8], a1[8];
#pragma unroll
    for (int i = 0; i < 8; ++i) { a0[i] = 0.f; a1[i] = 0.f; }

    for (int j = beg; j < end; j += 16) {
        const int j0 = j + g;
        const int j1 = j + 8 + g;
        const unsigned pk0 = edges[(j0 < end) ? j0 : (end - 1)];
        const unsigned pk1 = edges[(j1 < end) ? j1 : (end - 1)];
        float2 c0 = *(const float2*)&comp_l[(pk0 >> 16) * 2];
        float2 c1 = *(const float2*)&comp_l[(pk1 >> 16) * 2];
        if (j0 >= end) { c0.x = 0.f; c0.y = 0.f; }
        if (j1 >= end) { c1.x = 0.f; c1.y = 0.f; }
        const uint4 u0 = *(const uint4*)&x[(size_t)(pk0 & 0xFFFFu) * 64 + fo * 8];
        const uint4 u1 = *(const uint4*)&x[(size_t)(pk1 & 0xFFFFu) * 64 + fo * 8];
        float f0[8], f1[8];
        unpack8(u0, f0);
        unpack8(u1, f1);
#pragma unroll
        for (int i = 0; i < 8; ++i) {
            a0[i] = fmaf(c0.x, f0[i], a0[i]); a1[i] = fmaf(c0.y, f0[i], a1[i]);
            a0[i] = fmaf(c1.x, f1[i], a0[i]); a1[i] = fmaf(c1.y, f1[i], a1[i]);
        }
    }

#pragma unroll
    for (int m = 8; m <= 32; m <<= 1) {
#pragma unroll
        for (int i = 0; i < 8; ++i) {
            a0[i] += __shfl_xor(a0[i], m, 64);
            a1[i] += __shfl_xor(a1[i], m, 64);
        }
    }

    if (g == 0) {
        uint4 o0, o1;
        o0.x = (unsigned)f2bf(a0[0]) | ((unsigned)f2bf(a0[1]) << 16);
        o0.y = (unsigned)f2bf(a0[2]) | ((unsigned)f2bf(a0[3]) << 16);
        o0.z = (unsigned)f2bf(a0[4]) | ((unsigned)f2bf(a0[5]) << 16);
        o0.w = (unsigned)f2bf(a0[6]) | ((unsigned)f2bf(a0[7]) << 16);
        o1.x = (unsigned)f2bf(a1[0]) | ((unsigned)f2bf(a1[1]) << 16);
        o1.y = (unsigned)f2bf(a1[2]) | ((unsigned)f2bf(a1[3]) << 16);
        o1.z = (unsigned)f2bf(a1[4]) | ((unsigned)f2bf(a1[5]) << 16);
        o1.w = (unsigned)f2bf(a1[6]) | ((unsigned)f2bf(a1[7]) << 16);
        *(uint4*)&y[(size_t)n * 128 + fo * 8]      = o0;
        *(uint4*)&y[(size_t)n * 128 + 64 + fo * 8] = o1;
    }
}

// ---------------------------------------------------------------------------
// MFMA node transform: h[0:64] = U[64x192] @ W[192x64] + bias, where
// U = [y0,y1,x] per node (bf16), W held in registers (6 frags/wave).
// Wave w owns output cols [16w,16w+16); iterates 4 M-tiles of 16 nodes.
//  !FUSE: writes relu(h) as bf16 (layer-0 -> x1).
//  FUSE : accumulates h . fc_w into scalar (layer-1 + final dot).
// ---------------------------------------------------------------------------
template <bool FUSE>
__global__ __launch_bounds__(256) void mfma_transform(
    const ushort_t* __restrict__ y_bf,   // [N,128]
    const ushort_t* __restrict__ x_bf,   // [N,64]
    const ushort_t* __restrict__ Wt,     // [64,192] this layer (n-major)
    const float* __restrict__ bias,      // [64] f32
    const float* __restrict__ fcw,       // [N*64] (FUSE)
    ushort_t* __restrict__ xout,         // [N,64] (!FUSE)
    float* __restrict__ scalar)          // [1]    (FUSE)
{
    __shared__ __align__(16) ushort_t su[64 * 200];   // 200 = 192 + 8 pad
    __shared__ float sred[4];
    const int t = threadIdx.x;
    const int w = t >> 6;
    const int lane = t & 63;
    const int c16 = lane & 15;     // A-row / B-col / C-col index
    const int quad = lane >> 4;
    const int tile = blockIdx.x;

    // --- W fragments, once per wave (registers) ---
    bf16x8 wf[6];
#pragma unroll
    for (int kf = 0; kf < 6; ++kf)
        wf[kf] = *(const bf16x8*)&Wt[(w * 16 + c16) * 192 + kf * 32 + quad * 8];
    const float bv = bias[w * 16 + c16];

    // --- stage U tile: 64 nodes x 192 bf16 (rows padded to 200) ---
#pragma unroll
    for (int k = 0; k < 6; ++k) {
        const int cid = t + 256 * k;          // 0..1535
        const int row = cid / 24;
        const int part = cid % 24;
        const int n = tile * 64 + row;
        uint4 v = {0u, 0u, 0u, 0u};
        if (n < N_NODES) {
            v = (part < 16) ? *(const uint4*)&y_bf[(size_t)n * 128 + part * 8]
                            : *(const uint4*)&x_bf[(size_t)n * 64 + (part - 16) * 8];
        }
        *(uint4*)&su[row * 200 + part * 8] = v;
    }
    __syncthreads();

    float fsum = 0.f;
#pragma unroll
    for (int mt = 0; mt < 4; ++mt) {
        f32x4 acc = {bv, bv, bv, bv};
#pragma unroll
        for (int kf = 0; kf < 6; ++kf) {
            const bf16x8 af =
                *(const bf16x8*)&su[(mt * 16 + c16) * 200 + kf * 32 + quad * 8];
            acc = __builtin_amdgcn_mfma_f32_16x16x32_bf16(af, wf[kf], acc, 0, 0, 0);
        }
        const int nodeb = tile * 64 + mt * 16 + quad * 4;
        if (FUSE) {
#pragma unroll
            for (int r = 0; r < 4; ++r) {
                const int n = nodeb + r;
                if (n < N_NODES)
                    fsum += acc[r] * fcw[(size_t)n * 64 + w * 16 + c16];
            }
        } else {
#pragma unroll
            for (int r = 0; r < 4; ++r) {
                const int n = nodeb + r;
                if (n < N_NODES)
                    xout[(size_t)n * 64 + w * 16 + c16] = f2bf(fmaxf(acc[r], 0.f));
            }
        }
    }

    if (FUSE) {
#pragma unroll
        for (int off = 32; off; off >>= 1) fsum += __shfl_down(fsum, off, 64);
        if (lane == 0) sred[w] = fsum;
        __syncthreads();
        if (t == 0) atomicAdd(scalar, sred[0] + sred[1] + sred[2] + sred[3]);
    }
}

__global__ void final_sigmoid(const float* __restrict__ scalar,
                              const float* __restrict__ fcb,
                              float* __restrict__ out)
{
    const float v = scalar[0] + fcb[0];
    out[0] = 1.0f / (1.0f + expf(-v));
}

// ---------------------------------------------------------------------------
extern "C" void kernel_launch(void* const* d_in, const int* in_sizes, int n_in,
                              void* d_out, int out_size, void* d_ws, size_t ws_size,
                              hipStream_t stream)
{
    const float* features = (const float*)d_in[0];  // [50000, 64]
    const float* V        = (const float*)d_in[1];  // [2, 2, 64, 64]
    const float* comp     = (const float*)d_in[2];  // [2, 8, 2]
    const float* loop_w   = (const float*)d_in[3];  // [2, 64, 64]
    const float* bias     = (const float*)d_in[4];  // [2, 64]
    const float* fc_w     = (const float*)d_in[5];  // [1, 50000*64]
    const float* fc_b     = (const float*)d_in[6];  // [1]
    const int*   src      = (const int*)d_in[7];
    const int*   dst      = (const int*)d_in[8];
    const int*   etype    = (const int*)d_in[9];
    float* out = (float*)d_out;

    char* ws = (char*)d_ws;
    ushort_t*     y_bf    = (ushort_t*)(ws);                 // 12,800,000 B
    ushort_t*     x_bf    = (ushort_t*)(ws + 12800000);      //  6,400,000 B
    ushort_t*     x1_bf   = (ushort_t*)(ws + 19200000);      //  6,400,000 B
    ushort_t*     Wt      = (ushort_t*)(ws + 25600000);      //     49,152 B
    float*        scalar  = (float*)   (ws + 25649152);      //          4 B
    int*          deg     = (int*)     (ws + 25649168);      //    200,000 B
    int*          fill    = (int*)     (ws + 25849168);      //    200,000 B
    int*          row_ptr = (int*)     (ws + 26049168);      //    200,004 B
    unsigned int* edges   = (unsigned int*)(ws + 26249184);  //  3,200,000 B
    int*          bsum    = (int*)     (ws + 29449184);      //        784 B
    int*          bofs    = (int*)     (ws + 29450000);      //        784 B

    hipMemsetAsync(deg, 0, 400000, stream);   // deg + fill (contiguous)

    const int edgeBlocks = N_EDGES / 256;   // 3125
    const int aggBlocks  = N_NODES / 4;     // 12500
    const int mtBlocks   = (N_NODES + 63) / 64;  // 782

    // ---- prep (hist + bf16 converts) + CSR build ----
    prep_kernel<<<6346, 256, 0, stream>>>(dst, deg, features, x_bf, V, loop_w, Wt);
    scan_block_sums<<<SCAN_BLOCKS, 256, 0, stream>>>(deg, bsum);
    scan_offsets<<<1, 256, 0, stream>>>(bsum, bofs, row_ptr, scalar);
    scan_final<<<SCAN_BLOCKS, 256, 0, stream>>>(deg, bofs, row_ptr);
    scatter_kernel<<<edgeBlocks, 256, 0, stream>>>(src, dst, etype, row_ptr, fill, edges);

    // ---- layer 0 ----
    aggregate_bf<<<aggBlocks, 256, 0, stream>>>(x_bf, edges, row_ptr, comp, y_bf);
    mfma_transform<false><<<mtBlocks, 256, 0, stream>>>(
        y_bf, x_bf, Wt, bias, nullptr, x1_bf, nullptr);

    // ---- layer 1 + fused FC dot ----
    aggregate_bf<<<aggBlocks, 256, 0, stream>>>(x1_bf, edges, row_ptr, comp + 16, y_bf);
    mfma_transform<true><<<mtBlocks, 256, 0, stream>>>(
        y_bf, x1_bf, Wt + 12288, bias + 64, fc_w, nullptr, scalar);

    // ---- sigmoid ----
    final_sigmoid<<<1, 1, 0, stream>>>(scalar, fc_b, out);
}

// Round 5
// 207.757 us; speedup vs baseline: 7.7465x; 1.2396x over previous
//
#include <hip/hip_runtime.h>
#include <hip/hip_bf16.h>
#include <math.h>

#define N_NODES 50000
#define N_EDGES 800000
#define HDIM 64

#define NBUCKET 98        // buckets of 512 nodes: 98*512 = 50176 >= 50000
#define BSHIFT  9
#define BCAP    10240     // mean 8163, sd ~88 -> 23 sigma headroom

typedef short bf16x8 __attribute__((ext_vector_type(8)));
typedef float f32x4  __attribute__((ext_vector_type(4)));
typedef unsigned short ushort_t;

__device__ __forceinline__ ushort_t f2bf(float f) {
    __hip_bfloat16 b = __float2bfloat16(f);
    return *(ushort_t*)&b;
}
__device__ __forceinline__ void unpack8(uint4 u, float* f) {
    f[0] = __uint_as_float(u.x << 16); f[1] = __uint_as_float(u.x & 0xFFFF0000u);
    f[2] = __uint_as_float(u.y << 16); f[3] = __uint_as_float(u.y & 0xFFFF0000u);
    f[4] = __uint_as_float(u.z << 16); f[5] = __uint_as_float(u.z & 0xFFFF0000u);
    f[6] = __uint_as_float(u.w << 16); f[7] = __uint_as_float(u.w & 0xFFFF0000u);
}

// ---------------------------------------------------------------------------
// Prep: [0,3125) features->bf16; [3125,3221) W transpose+convert;
// block 3221: zero bucketFill + scalar.
// ---------------------------------------------------------------------------
__global__ __launch_bounds__(256) void prep_kernel(
    const float* __restrict__ features, ushort_t* __restrict__ x_bf,
    const float* __restrict__ V, const float* __restrict__ lw,
    ushort_t* __restrict__ Wt, int* __restrict__ bucketFill,
    float* __restrict__ scalar)
{
    const int b = blockIdx.x;
    const int t = threadIdx.x;
    if (b < 3125) {
        const int i = b * 256 + t;                   // < 800000 float4s
        const float4 v = ((const float4*)features)[i];
        ushort4 o = { f2bf(v.x), f2bf(v.y), f2bf(v.z), f2bf(v.w) };
        *(ushort4*)&x_bf[(size_t)i * 4] = o;
    } else if (b < 3221) {
        const int e = (b - 3125) * 256 + t;          // < 24576
        const int l = e / 12288, r = e % 12288;
        const int n = r / 192, k = r % 192;
        const int sel = k >> 6, i = k & 63;
        const float val = (sel < 2) ? V[l * 8192 + sel * 4096 + i * 64 + n]
                                    : lw[l * 4096 + i * 64 + n];
        Wt[e] = f2bf(val);
    } else {
        if (t < NBUCKET) bucketFill[t] = 0;
        if (t == NBUCKET) scalar[0] = 0.0f;
    }
}

// ---------------------------------------------------------------------------
// K1: bucket scatter. Each block takes 2048 edges, LDS-counts 98 dst-buckets,
// reserves per-(block,bucket) space with one global atomicAdd per bucket,
// appends packed payloads: src(16) | etype(3)<<16 | dstloc(9)<<19.
// Writes form ~98 contiguous runs per block -> no cross-XCD line sharing.
// ---------------------------------------------------------------------------
__global__ __launch_bounds__(256) void bucket_scatter(
    const int* __restrict__ src, const int* __restrict__ dst,
    const int* __restrict__ etype, int* __restrict__ bucketFill,
    unsigned int* __restrict__ buf)
{
    __shared__ int cnt[NBUCKET];
    __shared__ int base[NBUCKET];
    const int t = threadIdx.x;
    if (t < NBUCKET) cnt[t] = 0;
    __syncthreads();

    int rank[8], bkt[8];
    unsigned pay[8];
    bool valid[8];
#pragma unroll
    for (int k = 0; k < 8; ++k) {
        const int e = blockIdx.x * 2048 + k * 256 + t;
        valid[k] = (e < N_EDGES);
        if (valid[k]) {
            const int d = dst[e];
            const int b = d >> BSHIFT;
            bkt[k] = b;
            pay[k] = (unsigned)src[e] | ((unsigned)etype[e] << 16)
                   | ((unsigned)(d & 511) << 19);
            rank[k] = atomicAdd(&cnt[b], 1);
        }
    }
    __syncthreads();
    if (t < NBUCKET) base[t] = atomicAdd(&bucketFill[t], cnt[t]);
    __syncthreads();
#pragma unroll
    for (int k = 0; k < 8; ++k) {
        if (valid[k]) {
            const int pos = base[bkt[k]] + rank[k];
            if (pos < BCAP) buf[bkt[k] * BCAP + pos] = pay[k];
        }
    }
}

// ---------------------------------------------------------------------------
// K2: per-bucket sort. One block per bucket: hist over 512 local nodes,
// wave-scan, writes row_ptr (coalesced) and final edges into the bucket's
// private contiguous window (single-XCD writes, full-line evictions).
// ---------------------------------------------------------------------------
__global__ __launch_bounds__(256) void bucket_sort(
    const unsigned int* __restrict__ buf, const int* __restrict__ bucketFill,
    unsigned int* __restrict__ edges, int* __restrict__ row_ptr)
{
    __shared__ int hist[512];
    __shared__ int lscan[512];
    __shared__ int cnt2[512];
    __shared__ int sfill[128];
    __shared__ int sbase;
    const int b = blockIdx.x;
    const int t = threadIdx.x;

    hist[t] = 0; hist[t + 256] = 0;
    cnt2[t] = 0; cnt2[t + 256] = 0;
    if (t < NBUCKET) sfill[t] = bucketFill[t];
    else if (t < 128) sfill[t] = 0;
    __syncthreads();

    // exclusive prefix over bucket totals -> this bucket's base offset
    for (int off = 1; off < 128; off <<= 1) {
        int u = (t >= off && t < 128) ? sfill[t - off] : 0;
        __syncthreads();
        if (t < 128) sfill[t] += u;
        __syncthreads();
    }
    const int cntb = min(bucketFill[b], BCAP);
    if (t == 0) sbase = sfill[b] - bucketFill[b];
    __syncthreads();
    const int bb = sbase;

    // pass 1: node histogram
    for (int i = t; i < cntb; i += 256)
        atomicAdd(&hist[buf[b * BCAP + i] >> 19], 1);
    __syncthreads();

    // exclusive scan of 512 node counts: wave 0, 8 chunks of 64
    if (t < 64) {
        int carry = 0;
        for (int c = 0; c < 8; ++c) {
            const int h = hist[c * 64 + t];
            int x = h;
#pragma unroll
            for (int off = 1; off < 64; off <<= 1) {
                int u = __shfl_up(x, off, 64);
                if (t >= off) x += u;
            }
            lscan[c * 64 + t] = carry + x - h;
            carry += __shfl(x, 63, 64);
        }
    }
    __syncthreads();

    // row_ptr (coalesced)
    const int n0 = b << BSHIFT;
    for (int i = t; i < 512; i += 256) {
        const int g = n0 + i;
        if (g < N_NODES) row_ptr[g] = bb + lscan[i];
    }
    if (b == NBUCKET - 1 && t == 0) row_ptr[N_NODES] = bb + cntb;

    // pass 2: final placement within the bucket's contiguous window
    for (int i = t; i < cntb; i += 256) {
        const unsigned p = buf[b * BCAP + i];
        const int d = p >> 19;
        const int r = atomicAdd(&cnt2[d], 1);
        edges[bb + lscan[d] + r] = p & 0x7FFFFu;   // src | etype<<16
    }
}

// ---------------------------------------------------------------------------
// Aggregate (bf16 gather, f32 accumulate, bf16 out):
//   y[n,b,:] = sum_{e: dst=n} comp[etype_e][b] * x[src_e,:]
// One wave per node; 8 edge slots x 8 feature-octets; 2 chains -> 16 edges
// in flight per iteration. Butterfly fold over lane bits 3..5.
// ---------------------------------------------------------------------------
__global__ __launch_bounds__(256) void aggregate_bf(
    const ushort_t* __restrict__ x,      // [N,64] bf16
    const unsigned int* __restrict__ edges,
    const int* __restrict__ row_ptr,
    const float* __restrict__ comp_l,    // [8,2] f32
    ushort_t* __restrict__ y)            // [N,128] bf16
{
    const int lane = threadIdx.x & 63;
    const int n    = blockIdx.x * 4 + (threadIdx.x >> 6);
    const int g    = lane >> 3;
    const int fo   = lane & 7;

    const int beg = row_ptr[n];
    const int end = row_ptr[n + 1];

    float a0[8], a1[8];
#pragma unroll
    for (int i = 0; i < 8; ++i) { a0[i] = 0.f; a1[i] = 0.f; }

    for (int j = beg; j < end; j += 16) {
        const int j0 = j + g;
        const int j1 = j + 8 + g;
        const unsigned pk0 = edges[(j0 < end) ? j0 : (end - 1)];
        const unsigned pk1 = edges[(j1 < end) ? j1 : (end - 1)];
        float2 c0 = *(const float2*)&comp_l[(pk0 >> 16) * 2];
        float2 c1 = *(const float2*)&comp_l[(pk1 >> 16) * 2];
        if (j0 >= end) { c0.x = 0.f; c0.y = 0.f; }
        if (j1 >= end) { c1.x = 0.f; c1.y = 0.f; }
        const uint4 u0 = *(const uint4*)&x[(size_t)(pk0 & 0xFFFFu) * 64 + fo * 8];
        const uint4 u1 = *(const uint4*)&x[(size_t)(pk1 & 0xFFFFu) * 64 + fo * 8];
        float f0[8], f1[8];
        unpack8(u0, f0);
        unpack8(u1, f1);
#pragma unroll
        for (int i = 0; i < 8; ++i) {
            a0[i] = fmaf(c0.x, f0[i], a0[i]); a1[i] = fmaf(c0.y, f0[i], a1[i]);
            a0[i] = fmaf(c1.x, f1[i], a0[i]); a1[i] = fmaf(c1.y, f1[i], a1[i]);
        }
    }

#pragma unroll
    for (int m = 8; m <= 32; m <<= 1) {
#pragma unroll
        for (int i = 0; i < 8; ++i) {
            a0[i] += __shfl_xor(a0[i], m, 64);
            a1[i] += __shfl_xor(a1[i], m, 64);
        }
    }

    if (g == 0) {
        uint4 o0, o1;
        o0.x = (unsigned)f2bf(a0[0]) | ((unsigned)f2bf(a0[1]) << 16);
        o0.y = (unsigned)f2bf(a0[2]) | ((unsigned)f2bf(a0[3]) << 16);
        o0.z = (unsigned)f2bf(a0[4]) | ((unsigned)f2bf(a0[5]) << 16);
        o0.w = (unsigned)f2bf(a0[6]) | ((unsigned)f2bf(a0[7]) << 16);
        o1.x = (unsigned)f2bf(a1[0]) | ((unsigned)f2bf(a1[1]) << 16);
        o1.y = (unsigned)f2bf(a1[2]) | ((unsigned)f2bf(a1[3]) << 16);
        o1.z = (unsigned)f2bf(a1[4]) | ((unsigned)f2bf(a1[5]) << 16);
        o1.w = (unsigned)f2bf(a1[6]) | ((unsigned)f2bf(a1[7]) << 16);
        *(uint4*)&y[(size_t)n * 128 + fo * 8]      = o0;
        *(uint4*)&y[(size_t)n * 128 + 64 + fo * 8] = o1;
    }
}

// ---------------------------------------------------------------------------
// MFMA node transform: h[0:64] = U[64x192] @ W[192x64] + bias, U=[y0,y1,x]
// bf16, W in registers (6 frags/wave). Wave w owns output cols [16w,16w+16).
//  !FUSE: writes relu(h) bf16.  FUSE: accumulates h . fc_w into scalar.
// ---------------------------------------------------------------------------
template <bool FUSE>
__global__ __launch_bounds__(256) void mfma_transform(
    const ushort_t* __restrict__ y_bf,   // [N,128]
    const ushort_t* __restrict__ x_bf,   // [N,64]
    const ushort_t* __restrict__ Wt,     // [64,192] this layer (n-major)
    const float* __restrict__ bias,      // [64] f32
    const float* __restrict__ fcw,       // [N*64] (FUSE)
    ushort_t* __restrict__ xout,         // [N,64] (!FUSE)
    float* __restrict__ scalar)          // [1]    (FUSE)
{
    __shared__ __align__(16) ushort_t su[64 * 200];   // 200 = 192 + 8 pad
    __shared__ float sred[4];
    const int t = threadIdx.x;
    const int w = t >> 6;
    const int lane = t & 63;
    const int c16 = lane & 15;
    const int quad = lane >> 4;
    const int tile = blockIdx.x;

    bf16x8 wf[6];
#pragma unroll
    for (int kf = 0; kf < 6; ++kf)
        wf[kf] = *(const bf16x8*)&Wt[(w * 16 + c16) * 192 + kf * 32 + quad * 8];
    const float bv = bias[w * 16 + c16];

#pragma unroll
    for (int k = 0; k < 6; ++k) {
        const int cid = t + 256 * k;          // 0..1535
        const int row = cid / 24;
        const int part = cid % 24;
        const int n = tile * 64 + row;
        uint4 v = {0u, 0u, 0u, 0u};
        if (n < N_NODES) {
            v = (part < 16) ? *(const uint4*)&y_bf[(size_t)n * 128 + part * 8]
                            : *(const uint4*)&x_bf[(size_t)n * 64 + (part - 16) * 8];
        }
        *(uint4*)&su[row * 200 + part * 8] = v;
    }
    __syncthreads();

    float fsum = 0.f;
#pragma unroll
    for (int mt = 0; mt < 4; ++mt) {
        f32x4 acc = {bv, bv, bv, bv};
#pragma unroll
        for (int kf = 0; kf < 6; ++kf) {
            const bf16x8 af =
                *(const bf16x8*)&su[(mt * 16 + c16) * 200 + kf * 32 + quad * 8];
            acc = __builtin_amdgcn_mfma_f32_16x16x32_bf16(af, wf[kf], acc, 0, 0, 0);
        }
        const int nodeb = tile * 64 + mt * 16 + quad * 4;
        if (FUSE) {
#pragma unroll
            for (int r = 0; r < 4; ++r) {
                const int n = nodeb + r;
                if (n < N_NODES)
                    fsum += acc[r] * fcw[(size_t)n * 64 + w * 16 + c16];
            }
        } else {
#pragma unroll
            for (int r = 0; r < 4; ++r) {
                const int n = nodeb + r;
                if (n < N_NODES)
                    xout[(size_t)n * 64 + w * 16 + c16] = f2bf(fmaxf(acc[r], 0.f));
            }
        }
    }

    if (FUSE) {
#pragma unroll
        for (int off = 32; off; off >>= 1) fsum += __shfl_down(fsum, off, 64);
        if (lane == 0) sred[w] = fsum;
        __syncthreads();
        if (t == 0) atomicAdd(scalar, sred[0] + sred[1] + sred[2] + sred[3]);
    }
}

__global__ void final_sigmoid(const float* __restrict__ scalar,
                              const float* __restrict__ fcb,
                              float* __restrict__ out)
{
    const float v = scalar[0] + fcb[0];
    out[0] = 1.0f / (1.0f + expf(-v));
}

// ---------------------------------------------------------------------------
extern "C" void kernel_launch(void* const* d_in, const int* in_sizes, int n_in,
                              void* d_out, int out_size, void* d_ws, size_t ws_size,
                              hipStream_t stream)
{
    const float* features = (const float*)d_in[0];  // [50000, 64]
    const float* V        = (const float*)d_in[1];  // [2, 2, 64, 64]
    const float* comp     = (const float*)d_in[2];  // [2, 8, 2]
    const float* loop_w   = (const float*)d_in[3];  // [2, 64, 64]
    const float* bias     = (const float*)d_in[4];  // [2, 64]
    const float* fc_w     = (const float*)d_in[5];  // [1, 50000*64]
    const float* fc_b     = (const float*)d_in[6];  // [1]
    const int*   src      = (const int*)d_in[7];
    const int*   dst      = (const int*)d_in[8];
    const int*   etype    = (const int*)d_in[9];
    float* out = (float*)d_out;

    char* ws = (char*)d_ws;
    ushort_t*     y_bf    = (ushort_t*)(ws);                 // 12,800,000 B
    ushort_t*     x_bf    = (ushort_t*)(ws + 12800000);      //  6,400,000 B
    ushort_t*     x1_bf   = (ushort_t*)(ws + 19200000);      //  6,400,000 B
    ushort_t*     Wt      = (ushort_t*)(ws + 25600000);      //     49,152 B
    float*        scalar  = (float*)   (ws + 25649152);      //          4 B
    int*          bucketFill = (int*)  (ws + 25649280);      //        392 B
    int*          row_ptr = (int*)     (ws + 25649792);      //    200,004 B
    unsigned int* edges   = (unsigned int*)(ws + 25849856);  //  3,200,000 B
    unsigned int* buf     = (unsigned int*)(ws + 29049856);  //  4,014,080 B
                                                             // end ~33.1 MB

    const int aggBlocks = N_NODES / 4;          // 12500
    const int mtBlocks  = (N_NODES + 63) / 64;  // 782
    const int k1Blocks  = (N_EDGES + 2047) / 2048;  // 391

    // ---- prep (bf16 converts + zero counters) + bucketed CSR build ----
    prep_kernel<<<3222, 256, 0, stream>>>(features, x_bf, V, loop_w, Wt,
                                          bucketFill, scalar);
    bucket_scatter<<<k1Blocks, 256, 0, stream>>>(src, dst, etype, bucketFill, buf);
    bucket_sort<<<NBUCKET, 256, 0, stream>>>(buf, bucketFill, edges, row_ptr);

    // ---- layer 0 ----
    aggregate_bf<<<aggBlocks, 256, 0, stream>>>(x_bf, edges, row_ptr, comp, y_bf);
    mfma_transform<false><<<mtBlocks, 256, 0, stream>>>(
        y_bf, x_bf, Wt, bias, nullptr, x1_bf, nullptr);

    // ---- layer 1 + fused FC dot ----
    aggregate_bf<<<aggBlocks, 256, 0, stream>>>(x1_bf, edges, row_ptr, comp + 16, y_bf);
    mfma_transform<true><<<mtBlocks, 256, 0, stream>>>(
        y_bf, x1_bf, Wt + 12288, bias + 64, fc_w, nullptr, scalar);

    // ---- sigmoid ----
    final_sigmoid<<<1, 1, 0, stream>>>(scalar, fc_b, out);
}